// Round 4
// baseline (443.985 us; speedup 1.0000x reference)
//
#include <hip/hip_runtime.h>

#define NBINS 10
#define BLOCK 256
#define NW (BLOCK / 64)
#define GRID_MAX 2048

// Per element (t in {0,1} exactly):
//   u   = (1-2t)*x  (sign-bit xor: float_bits(1.0f)<<8 == 0x80000000)
//   e   = exp(-|u|);  g = sigmoid(u) = |sigmoid(x)-t|;  bce = softplus(u)
// Binning, exact reference semantics:
//   count bin j:  g>=E[j] && g<=E[j+1]  -> n_j = G[j] - U[j+1]
//                 (G[k]=#{g>=E[k]}, U[k]=#{g>E[k]}; boundaries double-counted)
//   assign bin j: g>=E[j] && g< E[j+1]  (later-bin-overwrite), summed directly
//                 in the SAME order as the previously-passing kernel.
// Mask liveness kept <=3 (prev, ge_k, gt_k) so lane-masks stay in SGPR pairs.
__device__ __forceinline__ void process_elem(float x, float tv,
                                             unsigned G[9], unsigned U[9],
                                             float fs[NBINS]) {
    const float E[NBINS + 1] = {0.0f, 0.1f, 0.2f, 0.3f, 0.4f, 0.5f,
                                0.6f, 0.7f, 0.8f, 0.9f, 1.000001f};
    float u   = __uint_as_float(__float_as_uint(x) ^ (__float_as_uint(tv) << 8));
    float au  = fabsf(u);
    float e   = __expf(-au);                    // v_exp path
    float ope = 1.0f + e;
    float r   = __builtin_amdgcn_rcpf(ope);     // v_rcp_f32
    float g   = (u >= 0.0f) ? r : e * r;        // sigmoid(u)
    float bce = fmaxf(u, 0.0f) + 0.69314718055994531f * __log2f(ope);

    bool prev = true;                            // g >= E[0] always
#pragma unroll
    for (int k = 1; k <= 9; ++k) {
        bool ge_k = (g >= E[k]);
        bool gt_k = (g >  E[k]);
        G[k - 1] += ge_k ? 1u : 0u;              // cumulative >= count
        U[k - 1] += gt_k ? 1u : 0u;              // cumulative >  count
        fs[k - 1] += (prev && !ge_k) ? bce : 0.0f;  // assignment-bin sum
        prev = ge_k;
    }
    fs[9] += prev ? bce : 0.0f;                  // g < E[10] always
}

// direct==0: write per-block partials to ws.  direct==1 (single block,
// ws-less fallback): compute the final loss and write out[0].
__global__ __launch_bounds__(BLOCK) void ghmc_main(
    const float* __restrict__ pred, const float* __restrict__ target,
    unsigned int* __restrict__ ws_cnt, float* __restrict__ ws_sum,
    long long nvec8, long long ntot, int direct, float* __restrict__ out) {
    unsigned G[9], U[9];
    float fs[NBINS];
#pragma unroll
    for (int k = 0; k < 9; ++k) { G[k] = 0u; U[k] = 0u; }
#pragma unroll
    for (int k = 0; k < NBINS; ++k) fs[k] = 0.0f;
    unsigned nloc = 0;

    const long long stride = (long long)gridDim.x * BLOCK;
    const long long tid0   = (long long)blockIdx.x * BLOCK + threadIdx.x;

    const float4* p4 = (const float4*)pred;
    const float4* t4 = (const float4*)target;
    for (long long i = tid0; i < nvec8; i += stride) {
        float4 p0 = p4[2 * i];
        float4 p1 = p4[2 * i + 1];
        float4 t0 = t4[2 * i];
        float4 t1 = t4[2 * i + 1];
        process_elem(p0.x, t0.x, G, U, fs);
        process_elem(p0.y, t0.y, G, U, fs);
        process_elem(p0.z, t0.z, G, U, fs);
        process_elem(p0.w, t0.w, G, U, fs);
        process_elem(p1.x, t1.x, G, U, fs);
        process_elem(p1.y, t1.y, G, U, fs);
        process_elem(p1.z, t1.z, G, U, fs);
        process_elem(p1.w, t1.w, G, U, fs);
        nloc += 8;
    }
    // scalar tail (n % 8 elements; empty for the bench shape)
    {
        long long base = nvec8 << 3;
        long long rem  = ntot - base;
        if (tid0 < rem) {
            process_elem(pred[base + tid0], target[base + tid0], G, U, fs);
            nloc += 1;
        }
    }

    // reconstruct exact per-bin inclusive counts from cumulative G/U
    unsigned cnt[NBINS];
    cnt[0] = nloc - U[0];                       // n_0 = N - #{g>E[1]}
#pragma unroll
    for (int j = 1; j <= 8; ++j) cnt[j] = G[j - 1] - U[j];
    cnt[9] = G[8];                              // U[10] == 0

    // wave (64-lane) down-reduction
#pragma unroll
    for (int k = 0; k < NBINS; ++k) {
        unsigned int c = cnt[k];
        float        s = fs[k];
#pragma unroll
        for (int off = 32; off > 0; off >>= 1) {
            c += __shfl_down(c, off, 64);
            s += __shfl_down(s, off, 64);
        }
        cnt[k] = c;
        fs[k]  = s;
    }

    __shared__ unsigned int scnt[NW][NBINS];
    __shared__ float        ssum[NW][NBINS];
    int lane = threadIdx.x & 63;
    int wid  = threadIdx.x >> 6;
    if (lane == 0) {
#pragma unroll
        for (int k = 0; k < NBINS; ++k) {
            scnt[wid][k] = cnt[k];
            ssum[wid][k] = fs[k];
        }
    }
    __syncthreads();
    if (threadIdx.x == 0) {
        if (direct) {
            double loss = 0.0;
#pragma unroll
            for (int k = 0; k < NBINS; ++k) {
                unsigned int c = 0;
                double       s = 0.0;
#pragma unroll
                for (int w = 0; w < NW; ++w) { c += scnt[w][k]; s += (double)ssum[w][k]; }
                loss += s / (double)(c > 0u ? c : 1u);
            }
            out[0] = (float)(0.075 * loss);     // GHM/10; `total` cancels
        } else {
#pragma unroll
            for (int k = 0; k < NBINS; ++k) {
                unsigned int c = 0;
                float        s = 0.0f;
#pragma unroll
                for (int w = 0; w < NW; ++w) { c += scnt[w][k]; s += ssum[w][k]; }
                ws_cnt[(long long)blockIdx.x * NBINS + k] = c;
                ws_sum[(long long)blockIdx.x * NBINS + k] = s;
            }
        }
    }
}

// Deterministic finalize: 1 block reduces per-block partials, computes loss.
__global__ __launch_bounds__(256) void ghmc_final(
    const unsigned int* __restrict__ ws_cnt, const float* __restrict__ ws_sum,
    int nblocks, float* __restrict__ out) {
    unsigned long long c[NBINS] = {};
    double             s[NBINS] = {};
    for (int b = threadIdx.x; b < nblocks; b += 256) {
#pragma unroll
        for (int k = 0; k < NBINS; ++k) {
            c[k] += ws_cnt[b * NBINS + k];
            s[k] += (double)ws_sum[b * NBINS + k];
        }
    }
#pragma unroll
    for (int k = 0; k < NBINS; ++k) {
        unsigned long long cc = c[k];
        double             ss = s[k];
#pragma unroll
        for (int off = 32; off > 0; off >>= 1) {
            cc += __shfl_down(cc, off, 64);
            ss += __shfl_down(ss, off, 64);
        }
        c[k] = cc;
        s[k] = ss;
    }
    __shared__ unsigned long long sc[4][NBINS];
    __shared__ double             sd[4][NBINS];
    int lane = threadIdx.x & 63;
    int wid  = threadIdx.x >> 6;
    if (lane == 0) {
#pragma unroll
        for (int k = 0; k < NBINS; ++k) { sc[wid][k] = c[k]; sd[wid][k] = s[k]; }
    }
    __syncthreads();
    if (threadIdx.x == 0) {
        double loss = 0.0;
#pragma unroll
        for (int k = 0; k < NBINS; ++k) {
            unsigned long long cc = 0;
            double             ss = 0.0;
#pragma unroll
            for (int w = 0; w < 4; ++w) { cc += sc[w][k]; ss += sd[w][k]; }
            loss += ss / (double)(cc > 0 ? cc : 1ull);
        }
        out[0] = (float)(0.075 * loss);         // GHM/10; `total` cancels
    }
}

extern "C" void kernel_launch(void* const* d_in, const int* in_sizes, int n_in,
                              void* d_out, int out_size, void* d_ws, size_t ws_size,
                              hipStream_t stream) {
    const float* pred   = (const float*)d_in[0];
    const float* target = (const float*)d_in[1];
    float*       out    = (float*)d_out;
    long long n     = (long long)in_sizes[0];
    long long nvec8 = n >> 3;

    // per-block partials: 10 uint + 10 float = 80 B
    const size_t per_block = NBINS * (sizeof(unsigned int) + sizeof(float));
    long long g = (nvec8 + BLOCK - 1) / BLOCK;
    if (g > GRID_MAX) g = GRID_MAX;                   // grid-stride the rest
    long long g_ws = (long long)(ws_size / per_block);
    if (g > g_ws) g = g_ws;

    if (g < 1) {
        // ws-less fallback: one block does everything (slow but correct)
        ghmc_main<<<1, BLOCK, 0, stream>>>(pred, target, nullptr, nullptr,
                                           nvec8, n, 1, out);
        return;
    }

    unsigned int* ws_cnt = (unsigned int*)d_ws;
    float*        ws_sum = (float*)((char*)d_ws + (size_t)g * NBINS * sizeof(unsigned int));

    ghmc_main<<<(int)g, BLOCK, 0, stream>>>(pred, target, ws_cnt, ws_sum,
                                            nvec8, n, 0, out);
    ghmc_final<<<1, 256, 0, stream>>>(ws_cnt, ws_sum, (int)g, out);
}

// Round 10
// 415.990 us; speedup vs baseline: 1.0673x; 1.0673x over previous
//
#include <hip/hip_runtime.h>

#define BLOCK 256
#define NW (BLOCK / 64)
#define GRID_MAX 2048

// u-space bin thresholds: L[k] = logit(E_k) where E_k is the EXACT float
// value of k/10 (computed in double).  g = sigmoid(u) >= E_k  <=>  u >= L[k].
// (u = (1-2t)*x via sign-bit xor; t in {0,1} exactly.)
__device__ __forceinline__ void process_u(float u, float a[10], unsigned G[10]) {
    const float L[10] = {0.0f,
        -2.1972245607794f, -1.3862943424934f, -0.8472978036209f,
        -0.4054650832729f,  0.0f,              0.4054652074492f,
         0.8472978036209f,  1.3862944356257f,  2.1972243124267f};
    // bce = softplus(u) = max(u,0) + ln2*log2(1+exp(-|u|))
    float e   = __expf(-fabsf(u));     // v_mul(log2e, -|u|) + v_exp
    float ope = 1.0f + e;
    float bce = fmaxf(u, 0.0f) + 0.693147180559945f * __log2f(ope);
    a[0] += bce;                       // total bce sum
#pragma unroll
    for (int k = 1; k <= 9; ++k) {
        bool m = (u >= L[k]);
        a[k] += m ? bce : 0.0f;                       // A[k] = sum bce [u>=L]
        G[k] += (unsigned)__popcll(__ballot(m));      // wave-count, SALU path
    }
}

__device__ __forceinline__ float make_u(float x, float tv) {
    return __uint_as_float(__float_as_uint(x) ^ (__float_as_uint(tv) << 8));
}

// direct==0: per-block partials {G[10], A[10]} to ws.
// direct==1: single block computes final loss (ws-less fallback).
__global__ __launch_bounds__(BLOCK) void ghmc_main(
    const float* __restrict__ pred, const float* __restrict__ target,
    unsigned int* __restrict__ ws_cnt, float* __restrict__ ws_sum,
    long long nvec8, long long ntot, int direct, float* __restrict__ out) {
    float    a[10];
    unsigned G[10];
#pragma unroll
    for (int k = 0; k < 10; ++k) { a[k] = 0.0f; G[k] = 0u; }

    const long long stride = (long long)gridDim.x * BLOCK;
    const long long tid0   = (long long)blockIdx.x * BLOCK + threadIdx.x;

    // main domain rounded DOWN to a wave multiple so every wave iteration is
    // fully convergent (ballot uniformity); residual done by block 0 below.
    const long long nvec8f = nvec8 & ~63LL;
    const float4* p4 = (const float4*)pred;
    const float4* t4 = (const float4*)target;
    for (long long i = tid0; i < nvec8f; i += stride) {
        float4 p0 = p4[2 * i];
        float4 p1 = p4[2 * i + 1];
        float4 t0 = t4[2 * i];
        float4 t1 = t4[2 * i + 1];
        process_u(make_u(p0.x, t0.x), a, G);
        process_u(make_u(p0.y, t0.y), a, G);
        process_u(make_u(p0.z, t0.z), a, G);
        process_u(make_u(p0.w, t0.w), a, G);
        process_u(make_u(p1.x, t1.x), a, G);
        process_u(make_u(p1.y, t1.y), a, G);
        process_u(make_u(p1.z, t1.z), a, G);
        process_u(make_u(p1.w, t1.w), a, G);
    }
    // residual: elements [nvec8f*8, ntot), < 64*8+8 = 520 elems.
    // Block 0 only, full-wave predicated (invalid lanes: u=-1e30 -> m=false,
    // bce = max(-1e30,0) + ln2*log2(1+exp(-inf)) = 0).
    if (blockIdx.x == 0) {
        long long base = nvec8f << 3;
        long long rem  = ntot - base;
        int niter = (int)((rem + BLOCK - 1) / BLOCK);   // block-uniform
        for (int it = 0; it < niter; ++it) {
            long long p = base + (long long)it * BLOCK + threadIdx.x;
            bool v = (p < ntot);
            long long pc = v ? p : 0;
            float x  = pred[pc];
            float tv = target[pc];
            float u  = v ? make_u(x, tv) : -1e30f;
            process_u(u, a, G);
        }
    }

    // wave reduction for float sums (G already wave-uniform via ballot)
#pragma unroll
    for (int k = 0; k < 10; ++k) {
        float s = a[k];
#pragma unroll
        for (int off = 32; off > 0; off >>= 1) s += __shfl_down(s, off, 64);
        a[k] = s;
    }

    __shared__ unsigned sG[NW][10];
    __shared__ float    sA[NW][10];
    int lane = threadIdx.x & 63;
    int wid  = threadIdx.x >> 6;
    if (lane == 0) {
#pragma unroll
        for (int k = 0; k < 10; ++k) { sG[wid][k] = G[k]; sA[wid][k] = a[k]; }
    }
    __syncthreads();
    if (threadIdx.x == 0) {
        unsigned gg[10];
        float    aa[10];
#pragma unroll
        for (int k = 0; k < 10; ++k) {
            unsigned c = 0; float s = 0.0f;
#pragma unroll
            for (int w = 0; w < NW; ++w) { c += sG[w][k]; s += sA[w][k]; }
            gg[k] = c; aa[k] = s;
        }
        if (direct) {
            // single block: gg/aa are the global totals
            double loss = 0.0;
#pragma unroll
            for (int j = 0; j < 10; ++j) {
                long long n = (j == 0) ? (long long)ntot - (long long)gg[1]
                            : (j == 9) ? (long long)gg[9]
                                       : (long long)gg[j] - (long long)gg[j + 1];
                double S = (j == 0) ? (double)aa[0] - (double)aa[1]
                         : (j == 9) ? (double)aa[9]
                                    : (double)aa[j] - (double)aa[j + 1];
                loss += S / (double)(n > 0 ? n : 1);
            }
            out[0] = (float)(0.075 * loss);   // GHM/10; `total` cancels
        } else {
#pragma unroll
            for (int k = 0; k < 10; ++k) {
                ws_cnt[(long long)blockIdx.x * 10 + k] = gg[k];
                ws_sum[(long long)blockIdx.x * 10 + k] = aa[k];
            }
        }
    }
}

// Deterministic finalize: 1 block sums per-block partials, telescopes,
// computes loss in double.
__global__ __launch_bounds__(256) void ghmc_final(
    const unsigned int* __restrict__ ws_cnt, const float* __restrict__ ws_sum,
    int nblocks, long long ntot, float* __restrict__ out) {
    unsigned long long c[10] = {};
    double             s[10] = {};
    for (int b = threadIdx.x; b < nblocks; b += 256) {
#pragma unroll
        for (int k = 0; k < 10; ++k) {
            c[k] += ws_cnt[b * 10 + k];
            s[k] += (double)ws_sum[b * 10 + k];
        }
    }
#pragma unroll
    for (int k = 0; k < 10; ++k) {
        unsigned long long cc = c[k];
        double             ss = s[k];
#pragma unroll
        for (int off = 32; off > 0; off >>= 1) {
            cc += __shfl_down(cc, off, 64);
            ss += __shfl_down(ss, off, 64);
        }
        c[k] = cc;
        s[k] = ss;
    }
    __shared__ unsigned long long sc[4][10];
    __shared__ double             sd[4][10];
    int lane = threadIdx.x & 63;
    int wid  = threadIdx.x >> 6;
    if (lane == 0) {
#pragma unroll
        for (int k = 0; k < 10; ++k) { sc[wid][k] = c[k]; sd[wid][k] = s[k]; }
    }
    __syncthreads();
    if (threadIdx.x == 0) {
        unsigned long long gg[11];
        double             aa[11];
#pragma unroll
        for (int k = 0; k < 10; ++k) {
            unsigned long long cc = 0; double ss = 0.0;
#pragma unroll
            for (int w = 0; w < 4; ++w) { cc += sc[w][k]; ss += sd[w][k]; }
            gg[k] = cc; aa[k] = ss;
        }
        gg[10] = 0ull; aa[10] = 0.0;
        gg[0]  = (unsigned long long)ntot;   // G[0] == total element count
        double loss = 0.0;
#pragma unroll
        for (int j = 0; j < 10; ++j) {
            long long n = (long long)gg[j] - (long long)gg[j + 1];
            double    S = aa[j] - aa[j + 1];
            loss += S / (double)(n > 0 ? n : 1);
        }
        out[0] = (float)(0.075 * loss);   // GHM/10; `total` cancels
    }
}

extern "C" void kernel_launch(void* const* d_in, const int* in_sizes, int n_in,
                              void* d_out, int out_size, void* d_ws, size_t ws_size,
                              hipStream_t stream) {
    const float* pred   = (const float*)d_in[0];
    const float* target = (const float*)d_in[1];
    float*       out    = (float*)d_out;
    long long n     = (long long)in_sizes[0];
    long long nvec8 = n >> 3;

    // per-block partials: 10 uint + 10 float = 80 B
    const size_t per_block = 10 * (sizeof(unsigned int) + sizeof(float));
    long long g = (nvec8 + BLOCK - 1) / BLOCK;
    if (g > GRID_MAX) g = GRID_MAX;
    long long g_ws = (long long)(ws_size / per_block);
    if (g > g_ws) g = g_ws;

    if (g < 1) {
        // ws-less fallback: one block does everything (slow but correct)
        ghmc_main<<<1, BLOCK, 0, stream>>>(pred, target, nullptr, nullptr,
                                           nvec8, n, 1, out);
        return;
    }

    unsigned int* ws_cnt = (unsigned int*)d_ws;
    float*        ws_sum = (float*)((char*)d_ws + (size_t)g * 10 * sizeof(unsigned int));

    ghmc_main<<<(int)g, BLOCK, 0, stream>>>(pred, target, ws_cnt, ws_sum,
                                            nvec8, n, 0, out);
    ghmc_final<<<1, 256, 0, stream>>>(ws_cnt, ws_sum, (int)g, n, out);
}